// Round 5
// baseline (302.182 us; speedup 1.0000x reference)
//
#include <hip/hip_runtime.h>
#include <math.h>

#define B_ 2
#define S_ 2048
#define DM 1024
#define NH 16
#define HD 64

typedef unsigned short u16;
typedef unsigned int u32;
typedef __attribute__((ext_vector_type(8))) short bf16x8;
typedef __attribute__((ext_vector_type(4))) float f32x4;

__device__ __forceinline__ u16 f2bf(float x) {
  unsigned u = __float_as_uint(x);
  u = (u + 0x7FFFu + ((u >> 16) & 1u)) >> 16;
  return (u16)u;
}

// packed f32 pair -> bf16 pair (low = first arg), single VALU op
__device__ __forceinline__ u32 cvtpk(float lo, float hi) {
  u32 r;
  asm("v_cvt_pk_bf16_f32 %0, %1, %2" : "=v"(r) : "v"(lo), "v"(hi));
  return r;
}

__device__ __forceinline__ float exp2a(float x) {
  float r;
  asm("v_exp_f32 %0, %1" : "=v"(r) : "v"(x));
  return r;
}

__device__ __forceinline__ void gload_lds16(const u16* g, u16* l) {
  __builtin_amdgcn_global_load_lds((const __attribute__((address_space(1))) void*)g,
                                   (__attribute__((address_space(3))) void*)l, 16, 0, 0);
}

__global__ void cvt_f32_bf16(const float* __restrict__ in, u16* __restrict__ out, int n4) {
  int i = blockIdx.x * blockDim.x + threadIdx.x;
  int stride = gridDim.x * blockDim.x;
  for (; i < n4; i += stride) {
    float4 v = ((const float4*)in)[i];
    ushort4 o;
    o.x = f2bf(v.x); o.y = f2bf(v.y); o.z = f2bf(v.z); o.w = f2bf(v.w);
    ((ushort4*)out)[i] = o;
  }
}

// C[M,N] = A[M,K] @ Bw[N,K]^T  (both bf16, fp32 accum). 128x128 tile, BK=32.
// MODE 0 (N=3072): scatter Q,K to (B,H,S,64); V written TRANSPOSED to
//   vt[(bh*64+d)*S + (s&~63) + pos(s&63)] with the sigma kv-permutation
//   pos(w) = 32*w5 + 8*((w>>2)&3) + 4*w4 + (w&3)  (bijective in 6 bits),
//   so attn's PV fragment is a single contiguous 16B read.
// MODE 1 (N=1024): f32 + bias to fo.
template <int MODE>
__global__ __launch_bounds__(256, 2) void gemm_bt(
    const u16* __restrict__ A, const u16* __restrict__ Bw, int K,
    u16* __restrict__ qo, u16* __restrict__ ko, u16* __restrict__ vo,
    float* __restrict__ fo, const float* __restrict__ bias, int N) {
  __shared__ __align__(16) u16 As[128 * 32];
  __shared__ __align__(16) u16 Bs[128 * 32];
  const int tid = threadIdx.x;
  const int wv = tid >> 6, lane = tid & 63;
  const int g = lane >> 4, c = lane & 15;
  const int wr = wv >> 1, wc = wv & 1;
  const int Mb = blockIdx.x * 128, Nb = blockIdx.y * 128;

  f32x4 acc[4][4];
#pragma unroll
  for (int i = 0; i < 4; i++)
#pragma unroll
    for (int j = 0; j < 4; j++) acc[i][j] = f32x4{0.f, 0.f, 0.f, 0.f};

  for (int kb = 0; kb < K; kb += 32) {
#pragma unroll
    for (int it = 0; it < 2; ++it) {
      int id = it * 256 + tid;
      int m = id >> 2, kk = (id & 3) * 8;
      gload_lds16(A + (size_t)(Mb + m) * K + kb + kk, As + (it * 4 + wv) * 512);
      gload_lds16(Bw + (size_t)(Nb + m) * K + kb + kk, Bs + (it * 4 + wv) * 512);
    }
    __syncthreads();
    bf16x8 af[4], bfr[4];
#pragma unroll
    for (int mi = 0; mi < 4; mi++)
      af[mi] = *(const bf16x8*)(As + (wr * 64 + mi * 16 + c) * 32 + g * 8);
#pragma unroll
    for (int ni = 0; ni < 4; ni++)
      bfr[ni] = *(const bf16x8*)(Bs + (wc * 64 + ni * 16 + c) * 32 + g * 8);
#pragma unroll
    for (int mi = 0; mi < 4; mi++)
#pragma unroll
      for (int ni = 0; ni < 4; ni++)
        acc[mi][ni] = __builtin_amdgcn_mfma_f32_16x16x32_bf16(af[mi], bfr[ni], acc[mi][ni], 0, 0, 0);
    __syncthreads();
  }

  if (MODE == 0) {
#pragma unroll
    for (int mi = 0; mi < 4; mi++) {
#pragma unroll
      for (int ni = 0; ni < 4; ni++) {
        int n = Nb + wc * 64 + ni * 16 + c;
        int which = n >> 10, nn = n & 1023;
        int h = nn >> 6, d = nn & 63;
        int row0 = Mb + wr * 64 + mi * 16 + g * 4;
        int b0 = row0 >> 11, s0 = row0 & 2047;
        if (which == 2) {
          // sigma-permuted V^T write, packed 8B
          int w6 = s0 & 63;
          int pos = ((w6 >> 5) << 5) | (((w6 >> 2) & 3) << 3) | (((w6 >> 4) & 1) << 2);
          uint2 o;
          o.x = cvtpk(acc[mi][ni][0], acc[mi][ni][1]);
          o.y = cvtpk(acc[mi][ni][2], acc[mi][ni][3]);
          *(uint2*)(vo + ((size_t)((b0 * NH + h) * HD + d)) * S_ + (s0 & ~63) + pos) = o;
        } else {
          u16* dst = (which == 0) ? qo : ko;
#pragma unroll
          for (int r = 0; r < 4; r++)
            dst[(((size_t)(b0 * NH + h)) * S_ + s0 + r) * HD + d] = f2bf(acc[mi][ni][r]);
        }
      }
    }
  } else {
#pragma unroll
    for (int mi = 0; mi < 4; mi++) {
#pragma unroll
      for (int ni = 0; ni < 4; ni++) {
        int n = Nb + wc * 64 + ni * 16 + c;
        float bv = bias[n];
#pragma unroll
        for (int r = 0; r < 4; r++) {
          int row = Mb + wr * 64 + mi * 16 + g * 4 + r;
          fo[(size_t)row * N + n] = acc[mi][ni][r] + bv;
        }
      }
    }
  }
}

// Flash attention, swapped-operand, NO K/V LDS staging (K/V tiles are L1/L2
// resident; all waves read identical fragments). No per-tile barriers -> waves
// run free. Grid 512 blocks x 512 thr (8 waves x 16 q-rows), XCD-swizzled so
// each XCD owns 4 bh (K/V L2-local). S^T = mfma(K,Q); softmax stats lane-
// uniform per q; exact defer-max skip; P frag from own regs under sigma
// k-order; V^T pre-permuted by producer -> single 16B global read per frag.
__global__ __launch_bounds__(512, 4) void attn_kernel(
    const u16* __restrict__ qb, const u16* __restrict__ kb,
    const u16* __restrict__ vtb, const int* __restrict__ kvm,
    u16* __restrict__ ob) {
  __shared__ float Madd[S_];

  const int tid = threadIdx.x;
  const int wv = tid >> 6, lane = tid & 63;
  const int g = lane >> 4, c = lane & 15;

  // XCD-aware bijective remap: 512 blocks, linear id L runs on XCD L%8.
  // Give XCD x the bh range [4x, 4x+4): bh = (L%8)*4 + (L/8)/16, qi = (L/8)%16.
  const int L = blockIdx.y * gridDim.x + blockIdx.x;
  const int j = L >> 3;
  const int bh = ((L & 7) << 2) | (j >> 4);
  const int qi = j & 15;
  const int b = bh >> 4, h = bh & 15;
  const int q0 = qi * 128;
  const size_t bhbase = (size_t)bh * (S_ * HD);

  // additive mask in exp2 domain: 0 for valid kv, -1e30 for masked
  for (int i = tid; i < S_; i += 512)
    Madd[i] = kvm[b * S_ + i] ? 0.f : -1e30f;
  __syncthreads();

  // Q fragment (B-operand: Q[q=q0+wv*16+c][k=d])
  bf16x8 qf[2];
#pragma unroll
  for (int ks = 0; ks < 2; ks++)
    qf[ks] = *(const bf16x8*)(qb + bhbase + (size_t)(q0 + wv * 16 + c) * HD + ks * 32 + g * 8);

  f32x4 Oa[4];  // [di], O^T: row=d(di*16+4g+r), col=q(c)
#pragma unroll
  for (int di = 0; di < 4; di++) Oa[di] = f32x4{0.f, 0.f, 0.f, 0.f};
  float mrun = -1e30f, lrun = 0.f;

  const float c2 = 0.03125f * 1.44269504088896f;  // (1/sqrt(1024)) * log2(e)

  const u16* kT = kb + bhbase;    // [kv][64]
  const u16* vT = vtb + bhbase;   // [d][2048], sigma-permuted per 64-chunk

  for (int kv0 = 0; kv0 < S_; kv0 += 64) {
    // K fragments straight from global (16B/lane, L1/L2-hit)
    bf16x8 kf[2][4];
#pragma unroll
    for (int ks = 0; ks < 2; ks++)
#pragma unroll
      for (int ni = 0; ni < 4; ni++)
        kf[ks][ni] = *(const bf16x8*)(kT + (kv0 + ni * 16 + c) * HD + ks * 32 + g * 8);

    // S^T: Sa[ni], row = kv (ni*16 + 4g + r), col = q (c)
    f32x4 Sa[4];
#pragma unroll
    for (int ni = 0; ni < 4; ni++) Sa[ni] = f32x4{0.f, 0.f, 0.f, 0.f};
    __builtin_amdgcn_s_setprio(1);
#pragma unroll
    for (int ks = 0; ks < 2; ks++)
#pragma unroll
      for (int ni = 0; ni < 4; ni++)
        Sa[ni] = __builtin_amdgcn_mfma_f32_16x16x32_bf16(kf[ks][ni], qf[ks], Sa[ni], 0, 0, 0);
    __builtin_amdgcn_s_setprio(0);

    // V^T fragments issued now; latency hides under softmax
    bf16x8 vf[2][4];
#pragma unroll
    for (int ks = 0; ks < 2; ks++)
#pragma unroll
      for (int di = 0; di < 4; di++)
        vf[ks][di] = *(const bf16x8*)(vT + (size_t)(di * 16 + c) * S_ + kv0 + ks * 32 + g * 8);

    // scale + additive mask (exp2 domain)
    f32x4 ma[4];
#pragma unroll
    for (int ni = 0; ni < 4; ni++)
      ma[ni] = *(const f32x4*)&Madd[kv0 + ni * 16 + g * 4];
#pragma unroll
    for (int ni = 0; ni < 4; ni++)
#pragma unroll
      for (int r = 0; r < 4; r++)
        Sa[ni][r] = Sa[ni][r] * c2 + ma[ni][r];

    // online softmax, exact defer-max: alpha==1 when no lane's max grows
    float tm = fmaxf(fmaxf(Sa[0][0], Sa[0][1]), fmaxf(Sa[0][2], Sa[0][3]));
#pragma unroll
    for (int ni = 1; ni < 4; ni++)
      tm = fmaxf(tm, fmaxf(fmaxf(Sa[ni][0], Sa[ni][1]), fmaxf(Sa[ni][2], Sa[ni][3])));
    tm = fmaxf(tm, __shfl_xor(tm, 16));
    tm = fmaxf(tm, __shfl_xor(tm, 32));
    if (__any(tm > mrun)) {
      float mnew = fmaxf(mrun, tm);
      float alpha = exp2a(mrun - mnew);
      mrun = mnew;
      lrun *= alpha;
#pragma unroll
      for (int di = 0; di < 4; di++)
#pragma unroll
        for (int r = 0; r < 4; r++) Oa[di][r] *= alpha;
    }
    float rs = 0.f;
#pragma unroll
    for (int ni = 0; ni < 4; ni++)
#pragma unroll
      for (int r = 0; r < 4; r++) {
        float p = exp2a(Sa[ni][r] - mrun);
        Sa[ni][r] = p;
        rs += p;
      }
    rs += __shfl_xor(rs, 16);
    rs += __shfl_xor(rs, 32);
    lrun += rs;

    // P frag from OWN regs (sigma k-order), packed with cvt_pk
    bf16x8 Pa[2];
#pragma unroll
    for (int ks = 0; ks < 2; ks++) {
      union { u32 u[4]; bf16x8 v; } pw;
      pw.u[0] = cvtpk(Sa[2 * ks][0], Sa[2 * ks][1]);
      pw.u[1] = cvtpk(Sa[2 * ks][2], Sa[2 * ks][3]);
      pw.u[2] = cvtpk(Sa[2 * ks + 1][0], Sa[2 * ks + 1][1]);
      pw.u[3] = cvtpk(Sa[2 * ks + 1][2], Sa[2 * ks + 1][3]);
      Pa[ks] = pw.v;
    }

    // O^T += V^T_frag * P_frag
    __builtin_amdgcn_s_setprio(1);
#pragma unroll
    for (int ks = 0; ks < 2; ks++)
#pragma unroll
      for (int di = 0; di < 4; di++)
        Oa[di] = __builtin_amdgcn_mfma_f32_16x16x32_bf16(vf[ks][di], Pa[ks], Oa[di], 0, 0, 0);
    __builtin_amdgcn_s_setprio(0);
  }

  // epilogue: lane (g,c) holds O^T[d = di*16+4g+r][q = c]; packed 8B stores
  float inv = 1.f / lrun;
  int q = q0 + wv * 16 + c;
  size_t base = ((size_t)(b * S_ + q)) * DM + (size_t)h * HD;
#pragma unroll
  for (int di = 0; di < 4; di++) {
    uint2 o;
    o.x = cvtpk(Oa[di][0] * inv, Oa[di][1] * inv);
    o.y = cvtpk(Oa[di][2] * inv, Oa[di][3] * inv);
    *(uint2*)(ob + base + di * 16 + g * 4) = o;
  }
}

extern "C" void kernel_launch(void* const* d_in, const int* in_sizes, int n_in,
                              void* d_out, int out_size, void* d_ws, size_t ws_size,
                              hipStream_t stream) {
  const float* q  = (const float*)d_in[0];
  const int* kvm  = (const int*)d_in[1];
  const float* Wq = (const float*)d_in[2];
  const float* Wk = (const float*)d_in[3];
  const float* Wv = (const float*)d_in[4];
  const float* Wo = (const float*)d_in[5];
  const float* bo = (const float*)d_in[6];
  float* out = (float*)d_out;
  char* ws = (char*)d_ws;

  u16* Xbf   = (u16*)(ws);                       // 8 MB (reused as obuf later)
  u16* Wcat  = (u16*)(ws + (8u << 20));          // 6 MB (Wq|Wk|Wv)
  u16* Wobf  = (u16*)(ws + (14u << 20));         // 2 MB
  u16* qbuf  = (u16*)(ws + (16u << 20));         // 8 MB (B,H,S,64)
  u16* kbuf  = (u16*)(ws + (24u << 20));         // 8 MB
  u16* vtbuf = (u16*)(ws + (40u << 20));         // 8 MB (B,H,64,S) sigma-permuted
  u16* obuf  = Xbf;                              // X dead after QKV GEMM

  cvt_f32_bf16<<<2048, 256, 0, stream>>>(q, Xbf, (B_ * S_ * DM) / 4);
  cvt_f32_bf16<<<512, 256, 0, stream>>>(Wq, Wcat, (DM * DM) / 4);
  cvt_f32_bf16<<<512, 256, 0, stream>>>(Wk, Wcat + DM * DM, (DM * DM) / 4);
  cvt_f32_bf16<<<512, 256, 0, stream>>>(Wv, Wcat + 2 * DM * DM, (DM * DM) / 4);
  cvt_f32_bf16<<<512, 256, 0, stream>>>(Wo, Wobf, (DM * DM) / 4);

  gemm_bt<0><<<dim3(32, 24), 256, 0, stream>>>(Xbf, Wcat, DM, qbuf, kbuf, vtbuf,
                                               nullptr, nullptr, 3 * DM);
  attn_kernel<<<dim3(16, 32), 512, 0, stream>>>(qbuf, kbuf, vtbuf, kvm, obuf);
  gemm_bt<1><<<dim3(32, 8), 256, 0, stream>>>(obuf, Wobf, DM, nullptr, nullptr,
                                              nullptr, out, bo, DM);
}

// Round 7
// 129.502 us; speedup vs baseline: 2.3334x; 2.3334x over previous
//
#include <hip/hip_runtime.h>
#include <math.h>

#define B_ 2
#define S_ 2048
#define DM 1024
#define NH 16
#define HD 64

typedef unsigned short u16;
typedef unsigned int u32;
typedef __attribute__((ext_vector_type(8))) short bf16x8;
typedef __attribute__((ext_vector_type(4))) float f32x4;

// (1/sqrt(model_dim)) * log2(e): folded into Q at GEMM0 epilogue
#define C2SCALE 0.0450842200277800f

__device__ __forceinline__ u16 f2bf(float x) {
  unsigned u = __float_as_uint(x);
  u = (u + 0x7FFFu + ((u >> 16) & 1u)) >> 16;
  return (u16)u;
}

// packed f32 pair -> bf16 pair (low = first arg), single VALU op
__device__ __forceinline__ u32 cvtpk(float lo, float hi) {
  u32 r;
  asm("v_cvt_pk_bf16_f32 %0, %1, %2" : "=v"(r) : "v"(lo), "v"(hi));
  return r;
}

__device__ __forceinline__ float exp2a(float x) {
  float r;
  asm("v_exp_f32 %0, %1" : "=v"(r) : "v"(x));
  return r;
}

__device__ __forceinline__ void gload_lds16(const u16* g, u16* l) {
  __builtin_amdgcn_global_load_lds((const __attribute__((address_space(1))) void*)g,
                                   (__attribute__((address_space(3))) void*)l, 16, 0, 0);
}

__global__ void cvt_f32_bf16(const float* __restrict__ in, u16* __restrict__ out, int n4) {
  int i = blockIdx.x * blockDim.x + threadIdx.x;
  int stride = gridDim.x * blockDim.x;
  for (; i < n4; i += stride) {
    float4 v = ((const float4*)in)[i];
    ushort4 o;
    o.x = f2bf(v.x); o.y = f2bf(v.y); o.z = f2bf(v.z); o.w = f2bf(v.w);
    ((ushort4*)out)[i] = o;
  }
}

// C[M,N] = A[M,K] @ Bw[N,K]^T  (both bf16, fp32 accum). 128x128 tile, BK=32.
// MODE 0 (N=3072): Q scattered PRE-SCALED by C2SCALE; K scattered; V written
//   TRANSPOSED to vt[(bh*64+d)*S + (s&~63) + pos(s&63)] with the sigma
//   kv-permutation pos(w) = 32*w5 + 8*((w>>2)&3) + 4*w4 + (w&3).
// MODE 1 (N=1024): f32 + bias to fo.
template <int MODE>
__global__ __launch_bounds__(256, 2) void gemm_bt(
    const u16* __restrict__ A, const u16* __restrict__ Bw, int K,
    u16* __restrict__ qo, u16* __restrict__ ko, u16* __restrict__ vo,
    float* __restrict__ fo, const float* __restrict__ bias, int N) {
  __shared__ __align__(16) u16 As[128 * 32];
  __shared__ __align__(16) u16 Bs[128 * 32];
  const int tid = threadIdx.x;
  const int wv = tid >> 6, lane = tid & 63;
  const int g = lane >> 4, c = lane & 15;
  const int wr = wv >> 1, wc = wv & 1;
  const int Mb = blockIdx.x * 128, Nb = blockIdx.y * 128;

  f32x4 acc[4][4];
#pragma unroll
  for (int i = 0; i < 4; i++)
#pragma unroll
    for (int j = 0; j < 4; j++) acc[i][j] = f32x4{0.f, 0.f, 0.f, 0.f};

  for (int kb = 0; kb < K; kb += 32) {
#pragma unroll
    for (int it = 0; it < 2; ++it) {
      int id = it * 256 + tid;
      int m = id >> 2, kk = (id & 3) * 8;
      gload_lds16(A + (size_t)(Mb + m) * K + kb + kk, As + (it * 4 + wv) * 512);
      gload_lds16(Bw + (size_t)(Nb + m) * K + kb + kk, Bs + (it * 4 + wv) * 512);
    }
    __syncthreads();
    bf16x8 af[4], bfr[4];
#pragma unroll
    for (int mi = 0; mi < 4; mi++)
      af[mi] = *(const bf16x8*)(As + (wr * 64 + mi * 16 + c) * 32 + g * 8);
#pragma unroll
    for (int ni = 0; ni < 4; ni++)
      bfr[ni] = *(const bf16x8*)(Bs + (wc * 64 + ni * 16 + c) * 32 + g * 8);
#pragma unroll
    for (int mi = 0; mi < 4; mi++)
#pragma unroll
      for (int ni = 0; ni < 4; ni++)
        acc[mi][ni] = __builtin_amdgcn_mfma_f32_16x16x32_bf16(af[mi], bfr[ni], acc[mi][ni], 0, 0, 0);
    __syncthreads();
  }

  if (MODE == 0) {
#pragma unroll
    for (int mi = 0; mi < 4; mi++) {
#pragma unroll
      for (int ni = 0; ni < 4; ni++) {
        int n = Nb + wc * 64 + ni * 16 + c;
        int which = n >> 10, nn = n & 1023;
        int h = nn >> 6, d = nn & 63;
        int row0 = Mb + wr * 64 + mi * 16 + g * 4;
        int b0 = row0 >> 11, s0 = row0 & 2047;
        if (which == 2) {
          // sigma-permuted V^T write, packed 8B
          int w6 = s0 & 63;
          int pos = ((w6 >> 5) << 5) | (((w6 >> 2) & 3) << 3) | (((w6 >> 4) & 1) << 2);
          uint2 o;
          o.x = cvtpk(acc[mi][ni][0], acc[mi][ni][1]);
          o.y = cvtpk(acc[mi][ni][2], acc[mi][ni][3]);
          *(uint2*)(vo + ((size_t)((b0 * NH + h) * HD + d)) * S_ + (s0 & ~63) + pos) = o;
        } else if (which == 0) {
#pragma unroll
          for (int r = 0; r < 4; r++)
            qo[(((size_t)(b0 * NH + h)) * S_ + s0 + r) * HD + d] =
                f2bf(acc[mi][ni][r] * C2SCALE);
        } else {
#pragma unroll
          for (int r = 0; r < 4; r++)
            ko[(((size_t)(b0 * NH + h)) * S_ + s0 + r) * HD + d] = f2bf(acc[mi][ni][r]);
        }
      }
    }
  } else {
#pragma unroll
    for (int mi = 0; mi < 4; mi++) {
#pragma unroll
      for (int ni = 0; ni < 4; ni++) {
        int n = Nb + wc * 64 + ni * 16 + c;
        float bv = bias[n];
#pragma unroll
        for (int r = 0; r < 4; r++) {
          int row = Mb + wr * 64 + mi * 16 + g * 4 + r;
          fo[(size_t)row * N + n] = acc[mi][ni][r] + bv;
        }
      }
    }
  }
}

// Flash attention, swapped-operand. Grid 512 blocks x 512 thr (8 waves x 16 q).
// Reg-staged double-buffered K/V LDS (T14): iter t = { ds_write tile t+1 from
// regs -> buf cur^1; issue global loads tile t+2 -> regs; compute buf cur;
// one barrier }. ds_write slot XOR-swizzled ((tid&7)^(srow&7)); reads use the
// same involution -> b128 reads spread over all 32 banks. No global_load_lds.
// S^T = mfma(K,Q) (Q pre-scaled by C2SCALE); softmax stats lane-uniform per q;
// exact defer-max; P frag from own regs under sigma k-order
//   sigma(ks,g,j) = 32ks + 16(j>>2) + 4g + (j&3)
// applied to BOTH PV operands (V^T pre-permuted by producer). O^T = mfma(V,P).
__global__ __launch_bounds__(512, 4) void attn_kernel(
    const u16* __restrict__ qb, const u16* __restrict__ kb,
    const u16* __restrict__ vtb, const int* __restrict__ kvm,
    u16* __restrict__ ob) {
  __shared__ __align__(16) u16 Kl[2][64 * 64];
  __shared__ __align__(16) u16 Vl[2][64 * 64];
  __shared__ __align__(16) float Madd[S_];

  const int tid = threadIdx.x;
  const int wv = tid >> 6, lane = tid & 63;
  const int g = lane >> 4, c = lane & 15;

  // XCD-aware bijective remap: XCD x owns bh range [4x,4x+4).
  const int L = blockIdx.y * gridDim.x + blockIdx.x;
  const int j = L >> 3;
  const int bh = ((L & 7) << 2) | (j >> 4);
  const int qi = j & 15;
  const int b = bh >> 4, h = bh & 15;
  const int q0 = qi * 128;
  const size_t bhbase = (size_t)bh * (S_ * HD);

  // additive mask in exp2 domain: 0 for valid kv, -1e30 for masked
  for (int i = tid; i < S_; i += 512)
    Madd[i] = kvm[b * S_ + i] ? 0.f : -1e30f;

  // Q fragment (B-operand: Q[q=q0+wv*16+c][k=d]), pre-scaled by producer
  bf16x8 qf[2];
#pragma unroll
  for (int ks = 0; ks < 2; ks++)
    qf[ks] = *(const bf16x8*)(qb + bhbase + (size_t)(q0 + wv * 16 + c) * HD + ks * 32 + g * 8);

  f32x4 Oa[4];  // [di], O^T: row=d(di*16+4g+r), col=q(c)
#pragma unroll
  for (int di = 0; di < 4; di++) Oa[di] = f32x4{0.f, 0.f, 0.f, 0.f};
  float mrun = -1e30f, lrun = 0.f;

  // staging geometry: thread stages 16B = global chunk (tid&7) of row srow,
  // written to LDS slot (tid&7)^(srow&7) (XOR-swizzled dest).
  const int srow = tid >> 3;
  const int scol8 = tid & 7;
  const u16* kg = kb + bhbase + srow * HD + scol8 * 8;            // +t*4096
  const u16* vg = vtb + bhbase + (size_t)srow * S_ + scol8 * 8;   // +t*64
  const int wslot = scol8 ^ (srow & 7);
  u16* kld = &Kl[0][srow * 64 + wslot * 8];                       // +buf*4096
  u16* vld = &Vl[0][srow * 64 + wslot * 8];

  // prologue: tile 0 -> regs -> buf0; tile 1 -> regs
  bf16x8 krg = *(const bf16x8*)kg;
  bf16x8 vrg = *(const bf16x8*)vg;
  *(bf16x8*)kld = krg;
  *(bf16x8*)vld = vrg;
  krg = *(const bf16x8*)(kg + 64 * HD);
  vrg = *(const bf16x8*)(vg + 64);
  __syncthreads();

  const int swz = c & 7;

  for (int t = 0; t < 32; ++t) {
    const int cur = t & 1;
    if (t + 1 < 32) {
      // tile t+1 regs -> buf cur^1 (prior reads of cur^1 ended before last barrier)
      *(bf16x8*)(kld + (cur ^ 1) * 4096) = krg;
      *(bf16x8*)(vld + (cur ^ 1) * 4096) = vrg;
      if (t + 2 < 32) {
        krg = *(const bf16x8*)(kg + (t + 2) * (64 * HD));
        vrg = *(const bf16x8*)(vg + (t + 2) * 64);
      }
    }
    const u16* KB = &Kl[cur][0];
    const u16* VB = &Vl[cur][0];

    // S^T: Sa[ni], row = kv (ni*16 + 4g + r), col = q (c)
    f32x4 Sa[4];
#pragma unroll
    for (int ni = 0; ni < 4; ni++) Sa[ni] = f32x4{0.f, 0.f, 0.f, 0.f};
    __builtin_amdgcn_s_setprio(1);
#pragma unroll
    for (int ks = 0; ks < 2; ks++) {
      bf16x8 kf[4];
#pragma unroll
      for (int ni = 0; ni < 4; ni++)
        kf[ni] = *(const bf16x8*)&KB[(ni * 16 + c) * 64 + (((4 * ks + g) ^ swz) * 8)];
#pragma unroll
      for (int ni = 0; ni < 4; ni++)
        Sa[ni] = __builtin_amdgcn_mfma_f32_16x16x32_bf16(kf[ni], qf[ks], Sa[ni], 0, 0, 0);
    }
    __builtin_amdgcn_s_setprio(0);

    // additive mask (broadcast LDS read per g-group)
    f32x4 ma[4];
#pragma unroll
    for (int ni = 0; ni < 4; ni++)
      ma[ni] = *(const f32x4*)&Madd[t * 64 + ni * 16 + g * 4];
#pragma unroll
    for (int ni = 0; ni < 4; ni++)
#pragma unroll
      for (int r = 0; r < 4; r++)
        Sa[ni][r] += ma[ni][r];

    // online softmax, exact defer-max (alpha==1 when no lane's max grows)
    float tm = fmaxf(fmaxf(Sa[0][0], Sa[0][1]), fmaxf(Sa[0][2], Sa[0][3]));
#pragma unroll
    for (int ni = 1; ni < 4; ni++)
      tm = fmaxf(tm, fmaxf(fmaxf(Sa[ni][0], Sa[ni][1]), fmaxf(Sa[ni][2], Sa[ni][3])));
    tm = fmaxf(tm, __shfl_xor(tm, 16));
    tm = fmaxf(tm, __shfl_xor(tm, 32));
    if (__any(tm > mrun)) {
      float mnew = fmaxf(mrun, tm);
      float alpha = exp2a(mrun - mnew);
      mrun = mnew;
      lrun *= alpha;
#pragma unroll
      for (int di = 0; di < 4; di++)
#pragma unroll
        for (int r = 0; r < 4; r++) Oa[di][r] *= alpha;
    }
    float rs = 0.f;
#pragma unroll
    for (int ni = 0; ni < 4; ni++)
#pragma unroll
      for (int r = 0; r < 4; r++) {
        float p = exp2a(Sa[ni][r] - mrun);
        Sa[ni][r] = p;
        rs += p;
      }
    rs += __shfl_xor(rs, 16);
    rs += __shfl_xor(rs, 32);
    lrun += rs;

    // P frag from OWN regs (sigma k-order), packed with cvt_pk
    bf16x8 Pa[2];
#pragma unroll
    for (int ks = 0; ks < 2; ks++) {
      union { u32 u[4]; bf16x8 v; } pw;
      pw.u[0] = cvtpk(Sa[2 * ks][0], Sa[2 * ks][1]);
      pw.u[1] = cvtpk(Sa[2 * ks][2], Sa[2 * ks][3]);
      pw.u[2] = cvtpk(Sa[2 * ks + 1][0], Sa[2 * ks + 1][1]);
      pw.u[3] = cvtpk(Sa[2 * ks + 1][2], Sa[2 * ks + 1][3]);
      Pa[ks] = pw.v;
    }

    // O^T += V^T_frag * P_frag (swizzled b128 reads)
    __builtin_amdgcn_s_setprio(1);
#pragma unroll
    for (int ks = 0; ks < 2; ks++) {
      bf16x8 vf[4];
#pragma unroll
      for (int di = 0; di < 4; di++)
        vf[di] = *(const bf16x8*)&VB[(di * 16 + c) * 64 + (((4 * ks + g) ^ swz) * 8)];
#pragma unroll
      for (int di = 0; di < 4; di++)
        Oa[di] = __builtin_amdgcn_mfma_f32_16x16x32_bf16(vf[di], Pa[ks], Oa[di], 0, 0, 0);
    }
    __builtin_amdgcn_s_setprio(0);

    __syncthreads();
  }

  // epilogue: lane (g,c) holds O^T[d = di*16+4g+r][q = c]; packed 8B stores
  float inv = 1.f / lrun;
  int q = q0 + wv * 16 + c;
  size_t base = ((size_t)(b * S_ + q)) * DM + (size_t)h * HD;
#pragma unroll
  for (int di = 0; di < 4; di++) {
    uint2 o;
    o.x = cvtpk(Oa[di][0] * inv, Oa[di][1] * inv);
    o.y = cvtpk(Oa[di][2] * inv, Oa[di][3] * inv);
    *(uint2*)(ob + base + di * 16 + g * 4) = o;
  }
}

extern "C" void kernel_launch(void* const* d_in, const int* in_sizes, int n_in,
                              void* d_out, int out_size, void* d_ws, size_t ws_size,
                              hipStream_t stream) {
  const float* q  = (const float*)d_in[0];
  const int* kvm  = (const int*)d_in[1];
  const float* Wq = (const float*)d_in[2];
  const float* Wk = (const float*)d_in[3];
  const float* Wv = (const float*)d_in[4];
  const float* Wo = (const float*)d_in[5];
  const float* bo = (const float*)d_in[6];
  float* out = (float*)d_out;
  char* ws = (char*)d_ws;

  u16* Xbf   = (u16*)(ws);                       // 8 MB (reused as obuf later)
  u16* Wcat  = (u16*)(ws + (8u << 20));          // 6 MB (Wq|Wk|Wv)
  u16* Wobf  = (u16*)(ws + (14u << 20));         // 2 MB
  u16* qbuf  = (u16*)(ws + (16u << 20));         // 8 MB (B,H,S,64), pre-scaled
  u16* kbuf  = (u16*)(ws + (24u << 20));         // 8 MB
  u16* vtbuf = (u16*)(ws + (40u << 20));         // 8 MB (B,H,64,S) sigma-permuted
  u16* obuf  = Xbf;                              // X dead after QKV GEMM

  cvt_f32_bf16<<<2048, 256, 0, stream>>>(q, Xbf, (B_ * S_ * DM) / 4);
  cvt_f32_bf16<<<512, 256, 0, stream>>>(Wq, Wcat, (DM * DM) / 4);
  cvt_f32_bf16<<<512, 256, 0, stream>>>(Wk, Wcat + DM * DM, (DM * DM) / 4);
  cvt_f32_bf16<<<512, 256, 0, stream>>>(Wv, Wcat + 2 * DM * DM, (DM * DM) / 4);
  cvt_f32_bf16<<<512, 256, 0, stream>>>(Wo, Wobf, (DM * DM) / 4);

  gemm_bt<0><<<dim3(32, 24), 256, 0, stream>>>(Xbf, Wcat, DM, qbuf, kbuf, vtbuf,
                                               nullptr, nullptr, 3 * DM);
  attn_kernel<<<dim3(16, 32), 512, 0, stream>>>(qbuf, kbuf, vtbuf, kvm, obuf);
  gemm_bt<1><<<dim3(32, 8), 256, 0, stream>>>(obuf, Wobf, DM, nullptr, nullptr,
                                              nullptr, out, bo, DM);
}